// Round 1
// baseline (211.822 us; speedup 1.0000x reference)
//
#include <hip/hip_runtime.h>

// Problem: E = sum over 4 directional diffs squared of (avgpool4(mean_c(org)) - avgpool4(mean_c(enh)))
// Key algebraic reduction: conv kernels are linear => compute p = pooled difference once,
// then E[y,x] = (p-pl)^2+(p-pr)^2+(p-pu)^2+(p-pd)^2 with zero-padded neighbors.
//
// Kernel 1: each thread owns one pooled pixel (b,py,px). It reads 3 channels x 4 rows
// of a float4 (the 4x4 window columns 4px..4px+3 are exactly float4 #px of a 512-wide row).
// Consecutive lanes read consecutive float4s -> perfectly coalesced 1 KiB/wave loads.
// Kernel 2: 5-point stencil on p (2 MB, L2-resident), writes E.

__global__ __launch_bounds__(256) void pool_diff_kernel(
    const float4* __restrict__ org, const float4* __restrict__ enh,
    float* __restrict__ p) {
  int idx = blockIdx.x * 256 + threadIdx.x;   // = b*16384 + py*128 + px
  int px = idx & 127;
  int py = (idx >> 7) & 127;
  int b  = idx >> 14;
  // float4 units: each 512-float row is 128 float4s.
  int base = b * 3 * 512 * 128 + py * 4 * 128 + px;
  float sum = 0.f;
#pragma unroll
  for (int c = 0; c < 3; ++c) {
#pragma unroll
    for (int dy = 0; dy < 4; ++dy) {
      int off = base + (c * 512 + dy) * 128;
      float4 o = org[off];
      float4 e = enh[off];
      sum += (o.x - e.x) + (o.y - e.y) + (o.z - e.z) + (o.w - e.w);
    }
  }
  p[idx] = sum * (1.0f / 48.0f);
}

__global__ __launch_bounds__(256) void espa_stencil_kernel(
    const float* __restrict__ p, float* __restrict__ out) {
  int idx = blockIdx.x * 256 + threadIdx.x;   // = b*16384 + y*128 + x
  int x = idx & 127;
  int y = (idx >> 7) & 127;
  float c = p[idx];
  float l = (x > 0)   ? p[idx - 1]   : 0.f;
  float r = (x < 127) ? p[idx + 1]   : 0.f;
  float u = (y > 0)   ? p[idx - 128] : 0.f;
  float d = (y < 127) ? p[idx + 128] : 0.f;
  float dl = c - l, dr = c - r, du = c - u, dd = c - d;
  out[idx] = dl * dl + dr * dr + du * du + dd * dd;
}

extern "C" void kernel_launch(void* const* d_in, const int* in_sizes, int n_in,
                              void* d_out, int out_size, void* d_ws, size_t ws_size,
                              hipStream_t stream) {
  const float4* org = (const float4*)d_in[0];
  const float4* enh = (const float4*)d_in[1];
  float* p   = (float*)d_ws;       // 32*128*128 floats = 2 MB scratch
  float* out = (float*)d_out;      // 32*1*128*128 floats

  const int N = 32 * 128 * 128;    // 524288 pooled pixels
  pool_diff_kernel<<<N / 256, 256, 0, stream>>>(org, enh, p);
  espa_stencil_kernel<<<N / 256, 256, 0, stream>>>(p, out);
}